// Round 11
// baseline (295.314 us; speedup 1.0000x reference)
//
#include <hip/hip_runtime.h>
#include <hip/hip_bf16.h>
#include <cstdint>
#include <cstddef>

// Problem constants
#define A_ 2
#define B_ 128
#define N_ 50000
#define D_ 512
#define E_ 4096
#define AB_ 256
#define CLIPV 1e-14f

// Workspace layout (float offsets)
static const size_t OFF_SYM   = 0;          // [AB_][N_] f32 symbolic; dead after k_enhagg -> outgemm partials
static const size_t OFF_SCORE = 12800000;   // [AB_][N_] p=exp(score); rows 0..127 overwritten in-place with agg f32
static const size_t OFF_TAIL  = 25600000;   // tail bf16 (131072 ushort)
static const size_t OFF_STATS = 25731072;   // stats block (2048 floats)
// stats sub-offsets
#define ST_SYMSUM 0
#define ST_EXPSUM 512
#define ST_AGGSUM 1024
// out-gemm split-K geometry
#define CH_K 384
#define OCHUNK 131   // ceil(50000/384)

typedef __attribute__((ext_vector_type(8))) short short8;
typedef __attribute__((ext_vector_type(4))) float f32x4;

// split f32 -> bf16 hi/lo via hardware cvt (rounding mode of hi irrelevant: lo compensates)
__device__ __forceinline__ void split_bf16(float f, unsigned short& h, unsigned short& lo) {
    __hip_bfloat16 bh = __float2bfloat16(f);
    float hf = __bfloat162float(bh);
    __hip_bfloat16 bl = __float2bfloat16(f - hf);
    h = *reinterpret_cast<unsigned short*>(&bh);
    lo = *reinterpret_cast<unsigned short*>(&bl);
}
__device__ __forceinline__ unsigned short to_bf16(float f) {
    __hip_bfloat16 bh = __float2bfloat16(f);
    return *reinterpret_cast<unsigned short*>(&bh);
}

// ---------------- tail = head + pred -> bf16 ----------------
__global__ __launch_bounds__(256) void k_tail(const float* __restrict__ head,
                                              const float* __restrict__ pred,
                                              unsigned short* __restrict__ tail_hi) {
    int i = blockIdx.x * 256 + threadIdx.x;
    if (i < AB_ * D_) {
        float t = head[i] + pred[i];
        tail_hi[i] = to_bf16(t);
    }
}

// ---------------- scatter-add symbolic ----------------
__global__ __launch_bounds__(256) void k_scatter(const float* __restrict__ hv,
                                                 const float* __restrict__ ev,
                                                 const int* __restrict__ es,
                                                 const int* __restrict__ ed,
                                                 float* __restrict__ sym) {
    int ab = blockIdx.x;
    const float* hvr = hv + (size_t)ab * N_;
    float* symr = sym + (size_t)ab * N_;
    int base = ab * E_;
    for (int e = threadIdx.x; e < E_; e += 256) {
        float v = ev[base + e];
        int s = es[base + e];
        int d = ed[base + e];
        atomicAdd(&symr[d], v * hvr[s]);
    }
}

// ---------------- masked sym row-sums ----------------
__global__ __launch_bounds__(256) void k_symsum(const float* __restrict__ sym,
                                                float* __restrict__ stats) {
    int ab = blockIdx.x >> 2, part = blockIdx.x & 3;
    const float4* src = reinterpret_cast<const float4*>(sym + (size_t)ab * N_ + part * 12500);
    float s = 0.f;
    for (int i = threadIdx.x; i < 3125; i += 256) {
        float4 v = src[i];
        s += ((v.x < CLIPV) ? 0.f : v.x) + ((v.y < CLIPV) ? 0.f : v.y)
           + ((v.z < CLIPV) ? 0.f : v.z) + ((v.w < CLIPV) ? 0.f : v.w);
    }
    __shared__ float red[256];
    red[threadIdx.x] = s;
    __syncthreads();
    for (int st = 128; st > 0; st >>= 1) {
        if (threadIdx.x < st) red[threadIdx.x] += red[threadIdx.x + st];
        __syncthreads();
    }
    if (threadIdx.x == 0) atomicAdd(&stats[ST_SYMSUM + ab], red[0]);
}

// ---------------- score GEMM: whole-K in LDS, ONE barrier, A direct from global, fused exp ----------------
// Block: 256 m x 64 n, 4 waves (wave tile 64x64). B (ent, 64 rows x K=512) staged ONCE into LDS
// (f32->bf16, pitch 520 ushorts: row stride = 4 banks -> 2-way aliasing only). A (tail bf16,
// 256 KB, L2-resident) read directly from global as 16-B fragments (16 rows x 64 B = coalesced).
// After the single barrier: 256 MFMA + 64 ds_read + 64 global frag loads per wave, no syncs.
#define SBP 520   // ushorts per LDS row

__global__ __launch_bounds__(256) void k_score(const float* __restrict__ ent,
                                               const unsigned short* __restrict__ tail_hi,
                                               float* __restrict__ p_out,
                                               float* __restrict__ stats) {
    __shared__ unsigned short lds[64 * SBP];   // 66560 B
    const int tid = threadIdx.x;
    const int w = tid >> 6;
    const int l = tid & 63;
    const int lm = l & 15;
    const int kg = l >> 4;
    const int n0 = blockIdx.x * 64;
    const int m0w = w * 64;

    // ---- stage B panel: 64 ent rows x 512 k, f32 -> bf16 ----
    {
        const int bn = tid >> 2;          // 0..63 row
        const int bc = tid & 3;           // 128-float segment
        int entrow = n0 + bn;
        if (entrow > N_ - 1) entrow = N_ - 1;
        const float* ep = ent + (size_t)entrow * D_ + bc * 128;
        unsigned short* lrow = &lds[bn * SBP + bc * 128];
        #pragma unroll
        for (int c = 0; c < 16; ++c) {
            float4 a = *reinterpret_cast<const float4*>(ep + c * 8);
            float4 b = *reinterpret_cast<const float4*>(ep + c * 8 + 4);
            short8 hb;
            hb[0]=(short)to_bf16(a.x); hb[1]=(short)to_bf16(a.y); hb[2]=(short)to_bf16(a.z); hb[3]=(short)to_bf16(a.w);
            hb[4]=(short)to_bf16(b.x); hb[5]=(short)to_bf16(b.y); hb[6]=(short)to_bf16(b.z); hb[7]=(short)to_bf16(b.w);
            *reinterpret_cast<short8*>(lrow + c * 8) = hb;
        }
    }
    __syncthreads();   // the only barrier

    f32x4 acc[4][4];
    #pragma unroll
    for (int i = 0; i < 4; ++i)
        #pragma unroll
        for (int j = 0; j < 4; ++j) acc[i][j] = (f32x4){0.f, 0.f, 0.f, 0.f};

    // A row base offsets (ushort units)
    const unsigned short* aBase = tail_hi + kg * 8;
    int aOff[4];
    #pragma unroll
    for (int mi = 0; mi < 4; ++mi) aOff[mi] = (m0w + mi * 16 + lm) * D_;
    const unsigned short* bBase = &lds[lm * SBP + kg * 8];

    #pragma unroll 4
    for (int ks = 0; ks < 16; ++ks) {
        const int kofs = ks * 32;
        short8 bh[4];
        #pragma unroll
        for (int nj = 0; nj < 4; ++nj)
            bh[nj] = *reinterpret_cast<const short8*>(bBase + nj * 16 * SBP + kofs);
        #pragma unroll
        for (int mi = 0; mi < 4; ++mi) {
            short8 ah = *reinterpret_cast<const short8*>(aBase + aOff[mi] + kofs);
            #pragma unroll
            for (int nj = 0; nj < 4; ++nj)
                acc[mi][nj] = __builtin_amdgcn_mfma_f32_16x16x32_bf16(ah, bh[nj], acc[mi][nj], 0, 0, 0);
        }
    }

    // epilogue: p = exp(score) (no max-sub; scores are small), store + per-row expsum
    #pragma unroll
    for (int mi = 0; mi < 4; ++mi) {
        #pragma unroll
        for (int j = 0; j < 4; ++j) {
            int row = m0w + mi * 16 + kg * 4 + j;
            float rsum = 0.f;
            #pragma unroll
            for (int nj = 0; nj < 4; ++nj) {
                int col = n0 + nj * 16 + lm;
                if (col < N_) {
                    float pv = expf(acc[mi][nj][j]);
                    p_out[(size_t)row * N_ + col] = pv;
                    rsum += pv;
                }
            }
            rsum += __shfl_xor(rsum, 1);
            rsum += __shfl_xor(rsum, 2);
            rsum += __shfl_xor(rsum, 4);
            rsum += __shfl_xor(rsum, 8);
            if (lm == 0) atomicAdd(&stats[ST_EXPSUM + row], rsum);
        }
    }
}

// ---------------- fused enhance + product + aggsum; agg f32 written IN PLACE over p rows 0..127 ----------------
__global__ __launch_bounds__(256) void k_enhagg(float* __restrict__ p,
                                                const float* __restrict__ sym,
                                                float* __restrict__ stats) {
    int b = blockIdx.x >> 2, part = blockIdx.x & 3;
    size_t off0 = (size_t)b * N_ + part * 12500;
    size_t off1 = (size_t)(128 + b) * N_ + part * 12500;
    float is0 = 1.f / fmaxf(CLIPV, stats[ST_SYMSUM + b]);
    float is1 = 1.f / fmaxf(CLIPV, stats[ST_SYMSUM + 128 + b]);
    float ie0 = 1.f / fmaxf(CLIPV, stats[ST_EXPSUM + b]);
    float ie1 = 1.f / fmaxf(CLIPV, stats[ST_EXPSUM + 128 + b]);
    const float4* s0p = reinterpret_cast<const float4*>(sym + off0);
    const float4* s1p = reinterpret_cast<const float4*>(sym + off1);
    float4* p0p = reinterpret_cast<float4*>(p + off0);
    const float4* p1p = reinterpret_cast<const float4*>(p + off1);
    float local = 0.f;
    for (int i = threadIdx.x; i < 3125; i += 256) {
        float4 s0 = s0p[i], s1 = s1p[i], q0 = p0p[i], q1 = p1p[i];
        float sv0[4] = {s0.x, s0.y, s0.z, s0.w};
        float sv1[4] = {s1.x, s1.y, s1.z, s1.w};
        float qv0[4] = {q0.x, q0.y, q0.z, q0.w};
        float qv1[4] = {q1.x, q1.y, q1.z, q1.w};
        float vv[4];
        #pragma unroll
        for (int c = 0; c < 4; ++c) {
            float a0 = (sv0[c] < CLIPV) ? 0.f : sv0[c];
            float a1 = (sv1[c] < CLIPV) ? 0.f : sv1[c];
            float e0 = a0 * is0 + qv0[c] * ie0; e0 = (e0 < CLIPV) ? 0.f : e0;
            float e1 = a1 * is1 + qv1[c] * ie1; e1 = (e1 < CLIPV) ? 0.f : e1;
            float v = e0 * e1 * 0.25f;
            v = (v < CLIPV) ? 0.f : v;
            local += v;
            vv[c] = v;
        }
        float4 o; o.x = vv[0]; o.y = vv[1]; o.z = vv[2]; o.w = vv[3];
        p0p[i] = o;
    }
    __shared__ float red[256];
    red[threadIdx.x] = local;
    __syncthreads();
    for (int st = 128; st > 0; st >>= 1) {
        if (threadIdx.x < st) red[threadIdx.x] += red[threadIdx.x + st];
        __syncthreads();
    }
    if (threadIdx.x == 0) atomicAdd(&stats[ST_AGGSUM + b], red[0]);
}

// ---------------- out GEMM via split-bf16 MFMA, split-K, double-buffered, 1 barrier/K-step ----------------
#define APITCH 40
#define OG_BUF 20480
#define OLDS_A_HI 0
#define OLDS_A_LO 5120
#define OLDS_B_HI 10240
#define OLDS_B_LO 15360

__global__ __launch_bounds__(256) void k_outgemm(const float* __restrict__ ent,
                                                 const float* __restrict__ aggf,
                                                 float* __restrict__ part) {
    __shared__ unsigned short lds[40960];   // 80 KB: 2 buffers
    const int bid = blockIdx.x;
    const int chunk = bid >> 2, dt = bid & 3;
    const int n0 = chunk * CH_K, d0 = dt * 128;
    const int tid = threadIdx.x;
    const int w = tid >> 6;
    const int l = tid & 63;
    const int lm = l & 15;
    const int kg = l >> 4;
    const int m0w = (w >> 1) * 64;
    const int c0w = (w & 1) * 64;

    f32x4 acc[4][4];
    #pragma unroll
    for (int i = 0; i < 4; ++i)
        #pragma unroll
        for (int j = 0; j < 4; ++j) acc[i][j] = (f32x4){0.f, 0.f, 0.f, 0.f};

    const int arow = tid >> 1;
    const int ahalf = tid & 1;
    const int dcol = tid & 127;
    const int bhalf = tid >> 7;
    const size_t entcol = (size_t)(d0 + dcol);

    float ra[16], rb[16];

    auto loadA = [&](int k0) {
        int nbase = n0 + k0 + ahalf * 16;
        const float* asrc = aggf + (size_t)arow * N_ + nbase;
        #pragma unroll
        for (int c = 0; c < 2; ++c) {
            if (nbase + c * 8 + 7 < N_) {
                float4 g0 = *reinterpret_cast<const float4*>(asrc + c * 8);
                float4 g1 = *reinterpret_cast<const float4*>(asrc + c * 8 + 4);
                ra[c*8+0]=g0.x; ra[c*8+1]=g0.y; ra[c*8+2]=g0.z; ra[c*8+3]=g0.w;
                ra[c*8+4]=g1.x; ra[c*8+5]=g1.y; ra[c*8+6]=g1.z; ra[c*8+7]=g1.w;
            } else {
                #pragma unroll
                for (int j = 0; j < 8; ++j) {
                    int n = nbase + c * 8 + j;
                    ra[c*8+j] = (n < N_) ? aggf[(size_t)arow * N_ + n] : 0.f;
                }
            }
        }
    };
    auto loadB = [&](int k0) {
        int nb = n0 + k0 + bhalf * 16;
        #pragma unroll
        for (int j = 0; j < 16; ++j) {
            int n = nb + j;
            if (n > N_ - 1) n = N_ - 1;
            rb[j] = ent[(size_t)n * D_ + entcol];
        }
    };
    auto stage = [&](int bufbase) {
        #pragma unroll
        for (int c = 0; c < 2; ++c) {
            short8 hb, lb;
            #pragma unroll
            for (int j = 0; j < 8; ++j) {
                unsigned short h, lo;
                split_bf16(ra[c*8+j], h, lo);
                hb[j] = (short)h;
                lb[j] = (short)lo;
            }
            *reinterpret_cast<short8*>(&lds[bufbase + OLDS_A_HI + arow * APITCH + ahalf * 16 + c * 8]) = hb;
            *reinterpret_cast<short8*>(&lds[bufbase + OLDS_A_LO + arow * APITCH + ahalf * 16 + c * 8]) = lb;
        }
        #pragma unroll
        for (int c = 0; c < 2; ++c) {
            short8 hb, lb;
            #pragma unroll
            for (int j = 0; j < 8; ++j) {
                unsigned short h, lo;
                split_bf16(rb[c*8+j], h, lo);
                hb[j] = (short)h;
                lb[j] = (short)lo;
            }
            *reinterpret_cast<short8*>(&lds[bufbase + OLDS_B_HI + dcol * APITCH + bhalf * 16 + c * 8]) = hb;
            *reinterpret_cast<short8*>(&lds[bufbase + OLDS_B_LO + dcol * APITCH + bhalf * 16 + c * 8]) = lb;
        }
    };

    // prologue: stage tile 0, prefetch regs for tile 1
    loadA(0); loadB(0);
    stage(0);
    loadA(32); loadB(32);
    __syncthreads();

    for (int t = 0; t < 12; ++t) {
        const int base = (t & 1) * OG_BUF;
        const int nb2 = ((t + 1) & 1) * OG_BUF;
        if (t < 11) stage(nb2);                       // regs hold tile t+1
        if (t < 10) { loadA((t + 2) * 32); loadB((t + 2) * 32); }
        short8 ah[4], al[4], bh[4], bl[4];
        #pragma unroll
        for (int mi = 0; mi < 4; ++mi) {
            int r = m0w + mi * 16 + lm;
            ah[mi] = *reinterpret_cast<const short8*>(&lds[base + OLDS_A_HI + r * APITCH + kg * 8]);
            al[mi] = *reinterpret_cast<const short8*>(&lds[base + OLDS_A_LO + r * APITCH + kg * 8]);
        }
        #pragma unroll
        for (int nj = 0; nj < 4; ++nj) {
            int r = c0w + nj * 16 + lm;
            bh[nj] = *reinterpret_cast<const short8*>(&lds[base + OLDS_B_HI + r * APITCH + kg * 8]);
            bl[nj] = *reinterpret_cast<const short8*>(&lds[base + OLDS_B_LO + r * APITCH + kg * 8]);
        }
        #pragma unroll
        for (int mi = 0; mi < 4; ++mi)
            #pragma unroll
            for (int nj = 0; nj < 4; ++nj) {
                acc[mi][nj] = __builtin_amdgcn_mfma_f32_16x16x32_bf16(ah[mi], bh[nj], acc[mi][nj], 0, 0, 0);
                acc[mi][nj] = __builtin_amdgcn_mfma_f32_16x16x32_bf16(ah[mi], bl[nj], acc[mi][nj], 0, 0, 0);
                acc[mi][nj] = __builtin_amdgcn_mfma_f32_16x16x32_bf16(al[mi], bh[nj], acc[mi][nj], 0, 0, 0);
            }
        __syncthreads();
    }

    float* pbase = part + (size_t)chunk * 65536;
    #pragma unroll
    for (int nj = 0; nj < 4; ++nj) {
        int dcolo = d0 + c0w + nj * 16 + lm;
        #pragma unroll
        for (int mi = 0; mi < 4; ++mi) {
            int brow = m0w + mi * 16 + kg * 4;
            #pragma unroll
            for (int j = 0; j < 4; ++j)
                pbase[(size_t)(brow + j) * 512 + dcolo] = acc[mi][nj][j];
        }
    }
}

// ---------------- reduce partials + normalize by agg_sum ----------------
__global__ __launch_bounds__(256) void k_redout(const float* __restrict__ part,
                                                const float* __restrict__ stats,
                                                float* __restrict__ out) {
    int i = blockIdx.x * 256 + threadIdx.x;  // 0..65535
    int b = i >> 9;
    float s = 0.f;
    for (int c = 0; c < OCHUNK; ++c) s += part[(size_t)c * 65536 + i];
    out[i] = s / fmaxf(CLIPV, stats[ST_AGGSUM + b]);
}

extern "C" void kernel_launch(void* const* d_in, const int* in_sizes, int n_in,
                              void* d_out, int out_size, void* d_ws, size_t ws_size,
                              hipStream_t stream) {
    const float* ent = (const float*)d_in[0];
    const float* hv  = (const float*)d_in[1];
    const float* he  = (const float*)d_in[2];
    const float* pe  = (const float*)d_in[3];
    const float* ev  = (const float*)d_in[4];
    const int*   es  = (const int*)d_in[5];
    const int*   ed  = (const int*)d_in[6];
    float* out = (float*)d_out;
    float* ws = (float*)d_ws;

    unsigned short* tail_hi = (unsigned short*)(ws + OFF_TAIL);

    hipMemsetAsync(ws + OFF_SYM, 0, (size_t)AB_ * N_ * sizeof(float), stream);
    hipMemsetAsync(ws + OFF_STATS, 0, 2048 * sizeof(float), stream);

    k_tail<<<512, 256, 0, stream>>>(he, pe, tail_hi);
    k_scatter<<<AB_, 256, 0, stream>>>(hv, ev, es, ed, ws + OFF_SYM);
    k_score<<<782, 256, 0, stream>>>(ent, tail_hi, ws + OFF_SCORE, ws + OFF_STATS);
    k_symsum<<<AB_ * 4, 256, 0, stream>>>(ws + OFF_SYM, ws + OFF_STATS);
    k_enhagg<<<B_ * 4, 256, 0, stream>>>(ws + OFF_SCORE, ws + OFF_SYM, ws + OFF_STATS);
    k_outgemm<<<OCHUNK * 4, 256, 0, stream>>>(ent, ws + OFF_SCORE, ws + OFF_SYM);
    k_redout<<<256, 256, 0, stream>>>(ws + OFF_SYM, ws + OFF_STATS, out);
}